// Round 2
// baseline (274.866 us; speedup 1.0000x reference)
//
#include <hip/hip_runtime.h>
#include <hip/hip_bf16.h>

#define TSEQ 2048
#define NHEAD 16
#define DM 1024
#define NBATCH 2
#define MTOK (NBATCH * TSEQ)   // 4096

typedef __attribute__((ext_vector_type(8))) short short8;
typedef __attribute__((ext_vector_type(4))) float floatx4;
typedef __attribute__((address_space(1))) const void gvoid;
typedef __attribute__((address_space(3))) void lvoid;

static __device__ __forceinline__ unsigned short f2bf(float f) {
    unsigned int u = __float_as_uint(f);
    return (unsigned short)((u + 0x7fffu + ((u >> 16) & 1u)) >> 16);
}
static __device__ __forceinline__ float bf2f(unsigned short h) {
    return __uint_as_float(((unsigned int)h) << 16);
}

// ---------------------------------------------------------------------------
// Pack x and the 6 weight matrices to split bf16 rows.
//   x      -> [hi(1024) | lo(1024)]
//   Wproj  -> [hi | lo]            (3-term proj GEMM needs lo)
//   Wq..Wv -> [hi | hi] DUPLICATED (qkv GEMM becomes one plain K=2048 GEMM)
//   Wq,Wk,Wq2,Wk2 rows additionally PER-HEAD INTERLEAVED:
//     d<32 -> (d>>3)*16 + (d&7) ; d>=32 -> ((d-32)>>3)*16 + 8 + (d&7)
//   so each 16-col C-fragment holds RoPE pairs at lanes cc / cc^8
//   (lane-local RoPE via shfl_xor; q and k share the permutation so QK^T
//   is invariant and attention is unchanged; Wv stays plain).
// blocks [0,4096) -> x ; [4096,10240) -> weights (1024 blocks each).
// ---------------------------------------------------------------------------
__global__ __launch_bounds__(256)
void pack_all_kernel(const float* __restrict__ x,
                     const float* __restrict__ w0, const float* __restrict__ w1,
                     const float* __restrict__ w2, const float* __restrict__ w3,
                     const float* __restrict__ w4, const float* __restrict__ w5,
                     unsigned short* __restrict__ dstX, unsigned short* __restrict__ dstW)
{
    const float* src;
    unsigned short* dst;
    int gid;
    bool dup = false, ilv = false;
    if (blockIdx.x < 4096) {
        src = x; dst = dstX;
        gid = blockIdx.x * 256 + threadIdx.x;
    } else {
        int wi = (blockIdx.x - 4096) >> 10;
        const float* srcs[6] = {w0, w1, w2, w3, w4, w5};
        src = srcs[wi];
        dst = dstW + (size_t)wi * 1024 * 2048;
        gid = ((blockIdx.x - 4096) & 1023) * 256 + threadIdx.x;
        dup = (wi != 0);
        ilv = (wi >= 1 && wi <= 4);   // Wq, Wk, Wq2, Wk2
    }
    int e   = gid * 4;
    int row = e >> 10;
    int col = e & 1023;
    float4 f = *(const float4*)(src + (size_t)row * 1024 + col);
    ushort4 hi, lo;
    hi.x = f2bf(f.x); lo.x = f2bf(f.x - bf2f(hi.x));
    hi.y = f2bf(f.y); lo.y = f2bf(f.y - bf2f(hi.y));
    hi.z = f2bf(f.z); lo.z = f2bf(f.z - bf2f(hi.z));
    hi.w = f2bf(f.w); lo.w = f2bf(f.w - bf2f(hi.w));
    int drow = row;
    if (ilv) {
        int hh = row >> 6, d = row & 63;
        int dd = (d < 32) ? ((d >> 3) * 16 + (d & 7))
                          : (((d - 32) >> 3) * 16 + 8 + (d & 7));
        drow = hh * 64 + dd;
    }
    *(ushort4*)(dst + (size_t)drow * 2048 + col)        = hi;
    *(ushort4*)(dst + (size_t)drow * 2048 + 1024 + col) = dup ? hi : lo;
}

// ---------------------------------------------------------------------------
// qkv GEMM, 4-phase pipelined schedule (T3+T4+T5):
//   C[4096][5120] = Xp[4096][2048] . Bdup[5120][2048]^T   (plain bf16 GEMM)
// Tile 256x320, K-tile 64 (two kh of 32), 512 threads = 8 waves laid out
// 2M x 4N: wave = 128 rows x 80 cols, acc 8x5 frags (160 regs).
// Per wave per K-tile: 26 ds_read_b128 (was 44 with 8Mx1N) vs 80 MFMA
//   -> per-CU LDS ~1700-2500cy < MFMA ~3100cy: MFMA-bound.
// Phases: p1 (kh0, M-half0 + B-read), p2 (kh0, M-half1), p3 (kh1, M-half0 +
// B-read), p4 (kh1, M-half1). Stages: p1->A-kh1(t+1), p2->B-kh1(t+1),
// p3->A-kh0(t+2), p4->B-kh0(t+2). Counted vmcnt(8) at p2/p4 only.
// lgkmcnt(0) before each barrier => every region's last read drains >=1
// barrier before its overwrite is issued. Chunk-XOR swizzle via pre-swizzled
// global source + linear global_load_lds dest (0 bank conflicts measured).
// Epilogue: lane-local RoPE via shfl_xor(8) on interleaved-packed heads.
// Grid 16x16 = 256 blocks = exactly 1/CU.
// ---------------------------------------------------------------------------
#define VMW(N) asm volatile("s_waitcnt vmcnt(" #N ")" ::: "memory")
#define LGKM0  asm volatile("s_waitcnt lgkmcnt(0)" ::: "memory")

__global__ __launch_bounds__(512, 2)
void gemm_qkv(const unsigned short* __restrict__ Ap,
              const unsigned short* __restrict__ Bp,
              unsigned short* __restrict__ Ch, unsigned short* __restrict__ Vt)
{
    __shared__ __align__(16) unsigned short A0s[2][8192];    // [256][32] each
    __shared__ __align__(16) unsigned short A1s[2][8192];
    __shared__ __align__(16) unsigned short B0s[2][10240];   // [320][32] each
    __shared__ __align__(16) unsigned short B1s[2][10240];

    const int t    = threadIdx.x;
    const int lane = t & 63;
    const int w    = t >> 6;
    const int wm   = w >> 2;          // M-half (0..1): 128 rows
    const int wn   = w & 3;           // N-quarter (0..3): 80 cols
    const int s    = lane & 15;
    const int g    = (lane >> 4) & 3;
    const int row0 = blockIdx.x * 256;
    const int col0 = blockIdx.y * 320;

    // read-side swizzled offsets (element units, 32-wide rows)
    const int cofs  = ((g ^ ((lane >> 1) & 3)) << 3);
    const int addrA = (wm * 128 + s) * 32 + cofs;   // + ii*512
    const int addrB = (wn * 80 + s) * 32 + cofs;    // + nf*512

    // stage-side pre-swizzled global source base (logical chunk per thread)
    const int alc = (t & 3) ^ ((t >> 3) & 3);
    const unsigned short* Ag = Ap + (size_t)(row0 + (t >> 2)) * 2048 + alc * 8;
    const unsigned short* Bg = Bp + (size_t)(col0 + (t >> 2)) * 2048 + alc * 8;

#define STAGE_A(dst, kofs) {                                                                              \
    __builtin_amdgcn_global_load_lds((gvoid*)(Ag + (kofs)),              (lvoid*)((dst) + t * 8),        16, 0, 0); \
    __builtin_amdgcn_global_load_lds((gvoid*)(Ag + (kofs) + 128 * 2048), (lvoid*)((dst) + 4096 + t * 8), 16, 0, 0); }

#define STAGE_B(dst, kofs) {                                                                              \
    __builtin_amdgcn_global_load_lds((gvoid*)(Bg + (kofs)),              (lvoid*)((dst) + t * 8),        16, 0, 0); \
    __builtin_amdgcn_global_load_lds((gvoid*)(Bg + (kofs) + 128 * 2048), (lvoid*)((dst) + 4096 + t * 8), 16, 0, 0); \
    if (t < 256)                                                                                          \
    __builtin_amdgcn_global_load_lds((gvoid*)(Bg + (kofs) + 256 * 2048), (lvoid*)((dst) + 8192 + t * 8), 16, 0, 0); }

    floatx4 acc[8][5];
    #pragma unroll
    for (int ii = 0; ii < 8; ++ii)
        #pragma unroll
        for (int nf = 0; nf < 5; ++nf)
            acc[ii][nf] = (floatx4)(0.0f);

    // ---- prologue: tile0 (kh0,kh1) and tile1 (kh0) ----
    STAGE_A(A0s[0], 0);
    STAGE_B(B0s[0], 0);
    STAGE_A(A1s[0], 32);
    STAGE_B(B1s[0], 32);
    STAGE_A(A0s[1], 64);
    STAGE_B(B0s[1], 64);
    VMW(4);                       // tile0 fully landed (newest 4-5 = tile1 kh0)
    __builtin_amdgcn_s_barrier();
    __builtin_amdgcn_sched_barrier(0);

#define MFMA_CLUSTER(IOFS)                                                                      \
    __builtin_amdgcn_s_setprio(1);                                                              \
    _Pragma("unroll")                                                                           \
    for (int ii = 0; ii < 4; ++ii)                                                              \
        _Pragma("unroll")                                                                       \
        for (int nf = 0; nf < 5; ++nf)                                                          \
            acc[(IOFS) + ii][nf] = __builtin_amdgcn_mfma_f32_16x16x32_bf16(af[ii], bf[nf], acc[(IOFS) + ii][nf], 0, 0, 0); \
    __builtin_amdgcn_s_setprio(0);

#define TILE_BODY(TAU, DO12, DO34, W2, W4)                                                      \
{                                                                                               \
    const int cur_ = (TAU) & 1;                                                                 \
    const unsigned short* a0k = A0s[cur_];                                                      \
    const unsigned short* a1k = A1s[cur_];                                                      \
    const unsigned short* b0k = B0s[cur_];                                                      \
    const unsigned short* b1k = B1s[cur_];                                                      \
    short8 af[4], bf[5];                                                                        \
    /* ---- p1: kh0, M-half0 + B-kh0 read ; stage (TAU+1) A-kh1 ---- */                         \
    _Pragma("unroll")                                                                           \
    for (int ii = 0; ii < 4; ++ii) af[ii] = *(const short8*)&a0k[addrA + ii * 512];             \
    _Pragma("unroll")                                                                           \
    for (int nf = 0; nf < 5; ++nf) bf[nf] = *(const short8*)&b0k[addrB + nf * 512];             \
    if (DO12) STAGE_A(A1s[cur_ ^ 1], ((TAU) + 1) * 64 + 32);                                    \
    LGKM0;                                                                                      \
    __builtin_amdgcn_s_barrier();                                                               \
    __builtin_amdgcn_sched_barrier(0);                                                          \
    MFMA_CLUSTER(0)                                                                             \
    /* ---- p2: kh0, M-half1 ; stage (TAU+1) B-kh1 ; vmcnt ---- */                              \
    _Pragma("unroll")                                                                           \
    for (int ii = 0; ii < 4; ++ii) af[ii] = *(const short8*)&a0k[addrA + (ii + 4) * 512];       \
    if (DO12) STAGE_B(B1s[cur_ ^ 1], ((TAU) + 1) * 64 + 32);                                    \
    LGKM0;                                                                                      \
    W2;                                                                                         \
    __builtin_amdgcn_s_barrier();                                                               \
    __builtin_amdgcn_sched_barrier(0);                                                          \
    MFMA_CLUSTER(4)                                                                             \
    /* ---- p3: kh1, M-half0 + B-kh1 read ; stage (TAU+2) A-kh0 ---- */                         \
    _Pragma("unroll")                                                                           \
    for (int ii = 0; ii < 4; ++ii) af[ii] = *(const short8*)&a1k[addrA + ii * 512];             \
    _Pragma("unroll")                                                                           \
    for (int nf = 0; nf < 5; ++nf) bf[nf] = *(const short8*)&b1k[addrB + nf * 512];             \
    if (DO34) STAGE_A(A0s[cur_], ((TAU) + 2) * 64);                                             \
    LGKM0;                                                                                      \
    __builtin_amdgcn_s_barrier();                                                               \
    __builtin_amdgcn_sched_barrier(0);                                                          \
    MFMA_CLUSTER(0)                                                                             \
    /* ---- p4: kh1, M-half1 ; stage (TAU+2) B-kh0 ; vmcnt ---- */                              \
    _Pragma("unroll")                                                                           \
    for (int ii = 0; ii < 4; ++ii) af[ii] = *(const short8*)&a1k[addrA + (ii + 4) * 512];       \
    if (DO34) STAGE_B(B0s[cur_], ((TAU) + 2) * 64);                                             \
    LGKM0;                                                                                      \
    W4;                                                                                         \
    __builtin_amdgcn_s_barrier();                                                               \
    __builtin_amdgcn_sched_barrier(0);                                                          \
    MFMA_CLUSTER(4)                                                                             \
}

    #pragma unroll 2
    for (int tau = 0; tau < 30; ++tau)
        TILE_BODY(tau, 1, 1, VMW(8), VMW(8));
    TILE_BODY(30, 1, 0, VMW(8), VMW(4));
    TILE_BODY(31, 0, 0, VMW(0), ((void)0));

#undef TILE_BODY
#undef MFMA_CLUSTER
#undef STAGE_A
#undef STAGE_B

    // ---- epilogue: lane-local RoPE (+1/64 q-scale); V transposed ----
    const int cr = (lane >> 4) * 4;
    const int cc = lane & 15;
    const int rwbase = row0 + wm * 128;
    const float L2C = -0.41524101186092029f;  // -log2(10000)/32

    #pragma unroll
    for (int nf = 0; nf < 5; ++nf) {
        const int cg = col0 + wn * 80 + nf * 16;  // global col of this frag
        const int p  = cg >> 10;                  // 0=q 1=k 2=q2 3=k2 4=v
        const int h  = (cg >> 6) & 15;
        const int f  = (cg >> 4) & 3;
        if (p < 4) {
            const float sc  = (p == 0 || p == 2) ? 0.015625f : 1.0f;
            const float inv = exp2f((float)(f * 8 + (cc & 7)) * L2C);
            unsigned short* hp = Ch + (size_t)p * 4194304;
            #pragma unroll
            for (int ii = 0; ii < 8; ++ii) {
                int r0  = rwbase + ii * 16 + cr;
                int bhi = ((r0 >> 11) << 4) + h;
                size_t base = ((size_t)bhi * 2048 + (r0 & 2047)) * 64;
                #pragma unroll
                for (int rr = 0; rr < 4; ++rr) {
                    float tt = (float)((r0 + rr) & 2047);
                    float s0, c0;
                    __sincosf(tt * inv, &s0, &c0);
                    float x  = acc[ii][nf][rr];
                    float xp = __shfl_xor(x, 8, 64);
                    float y  = (cc < 8) ? (x * c0 + xp * s0) : (x * c0 - xp * s0);
                    hp[base + (size_t)rr * 64 + (f * 16 + cc)] = f2bf(y * sc);
                }
            }
        } else {
            #pragma unroll
            for (int ii = 0; ii < 8; ++ii) {
                int r0  = rwbase + ii * 16 + cr;
                int bhi = ((r0 >> 11) << 4) + h;
                int d   = f * 16 + cc;
                ushort4 o;
                o.x = f2bf(acc[ii][nf][0]); o.y = f2bf(acc[ii][nf][1]);
                o.z = f2bf(acc[ii][nf][2]); o.w = f2bf(acc[ii][nf][3]);
                *(ushort4*)(Vt + ((size_t)bhi * 64 + d) * 2048 + (r0 & 2047)) = o;
            }
        }
    }
}

// ---------------------------------------------------------------------------
// Output projection: C = (hiA+loA)*hiB^T + hiA*loB^T (3-term), fp32 out.
// Tile 128x64, grid (32,16)=512 blocks (2/CU), 24 KB LDS, wave-tile 64x32.
// ---------------------------------------------------------------------------
__global__ __launch_bounds__(256)
void gemm_proj(const unsigned short* __restrict__ Ap,
               const unsigned short* __restrict__ Bp,
               float* __restrict__ Cf)
{
    __shared__ __align__(16) unsigned short Ah[128 * 32];
    __shared__ __align__(16) unsigned short Al[128 * 32];
    __shared__ __align__(16) unsigned short Bh[64 * 32];
    __shared__ __align__(16) unsigned short Bl[64 * 32];

    const int t    = threadIdx.x;
    const int lane = t & 63;
    const int s    = lane & 15;
    const int row0 = blockIdx.x * 128;
    const int col0 = blockIdx.y * 64;
    const int m0   = ((t >> 6) >> 1) * 64;
    const int n0   = ((t >> 6) & 1) * 32;

    floatx4 acc[4][2];
    #pragma unroll
    for (int i = 0; i < 4; ++i)
        #pragma unroll
        for (int j = 0; j < 2; ++j)
            acc[i][j] = (floatx4)(0.0f);

    const int sr  = t >> 2;
    const int skx = ((t & 3) ^ ((t >> 3) & 3)) * 8;
    char* dA  = (char*)Ah + (size_t)t * 16;
    char* dAl = (char*)Al + (size_t)t * 16;
    char* dB  = (char*)Bh + (size_t)t * 16;
    char* dBl = (char*)Bl + (size_t)t * 16;
    const size_t arow = (size_t)(row0 + sr) * 2048 + skx;
    const size_t brow = (size_t)(col0 + sr) * 2048 + skx;   // sr in [0,64)

    #define ISSUE(k0)                                                                         \
    {                                                                                         \
        const unsigned short* ga = Ap + arow + (k0);                                          \
        const unsigned short* gb = Bp + brow + (k0);                                          \
        __builtin_amdgcn_global_load_lds((gvoid*)ga,                 (lvoid*)dA,          16, 0, 0); \
        __builtin_amdgcn_global_load_lds((gvoid*)(ga + 64*2048),     (lvoid*)(dA + 4096), 16, 0, 0); \
        __builtin_amdgcn_global_load_lds((gvoid*)(ga + 1024),        (lvoid*)dAl,         16, 0, 0); \
        __builtin_amdgcn_global_load_lds((gvoid*)(ga + 1024+64*2048),(lvoid*)(dAl + 4096),16, 0, 0); \
        __builtin_amdgcn_global_load_lds((gvoid*)gb,                 (lvoid*)dB,          16, 0, 0); \
        __builtin_amdgcn_global_load_lds((gvoid*)(gb + 1024),        (lvoid*)dBl,         16, 0, 0); \
    }

    const int cofs = (((lane >> 4) ^ ((lane >> 1) & 3)) << 3);

    ISSUE(0);
    for (int ks = 0; ks < 32; ++ks) {
        __syncthreads();
        short8 ahf[4], alf[4], bhf[2], blf[2];
        #pragma unroll
        for (int i = 0; i < 4; ++i) {
            int ra = (m0 + i * 16 + s) * 32 + cofs;
            ahf[i] = *(const short8*)&Ah[ra];
            alf[i] = *(const short8*)&Al[ra];
        }
        #pragma unroll
        for (int j = 0; j < 2; ++j) {
            int rb = (n0 + j * 16 + s) * 32 + cofs;
            bhf[j] = *(const short8*)&Bh[rb];
            blf[j] = *(const short8*)&Bl[rb];
        }
        #pragma unroll
        for (int i = 0; i < 4; ++i)
            #pragma unroll
            for (int j = 0; j < 2; ++j) {
                acc[i][j] = __builtin_amdgcn_mfma_f32_16x16x32_bf16(ahf[i], bhf[j], acc[i][j], 0, 0, 0);
                acc[i][j] = __builtin_amdgcn_mfma_f32_16x16x32_bf16(alf[i], bhf[j], acc[i][j], 0, 0, 0);
                acc[i][j] = __builtin_amdgcn_mfma_f32_16x16x32_bf16(ahf[i], blf[j], acc[i][j], 0, 0, 0);
            }
        __syncthreads();
        if (ks + 1 < 32) ISSUE((ks + 1) * 32);
    }
    #undef ISSUE

    const int cr = (lane >> 4) * 4;
    const int cc = lane & 15;
    #pragma unroll
    for (int i = 0; i < 4; ++i)
        #pragma unroll
        for (int j = 0; j < 2; ++j) {
            int r = row0 + m0 + i * 16 + cr;
            int c = col0 + n0 + j * 16 + cc;
            #pragma unroll
            for (int rr = 0; rr < 4; ++rr)
                Cf[(size_t)(r + rr) * 1024 + c] = acc[i][j][rr];
        }
}

// ---------------------------------------------------------------------------
// MFMA bilinear causal attention, S-transposed, q-frags hoisted to registers.
// psq overlays qs/q2s (dead after the one-time q-frag hoist) => 3 barriers/iter.
// LDS 80 KB, 2 blocks/CU.
// ---------------------------------------------------------------------------
__global__ __launch_bounds__(256, 2)
void attn_mfma(const unsigned short* __restrict__ qh, const unsigned short* __restrict__ q2h,
               const unsigned short* __restrict__ kh, const unsigned short* __restrict__ k2h,
               const unsigned short* __restrict__ vt, unsigned short* __restrict__ zout)
{
    __shared__ __align__(16) unsigned short smem[40960];   // 80 KB
    unsigned short* qs  = smem;              // [128][64] rot8 (init only)
    unsigned short* q2s = smem + 8192;
    unsigned short* psq = smem;              // [128][128] rot16, overlays qs/q2s
    unsigned short* ks  = smem + 16384;      // [128][64] rot8
    unsigned short* k2s = smem + 24576;
    unsigned short* vts = smem + 32768;      // [64][128] rot16

    const int bh = blockIdx.y;
    const int qt = (bh < 16) ? (15 - blockIdx.x) : blockIdx.x;  // pair heavy+light
    const int t  = threadIdx.x;
    const int lane = t & 63;
    const int w    = t >> 6;
    const int s    = lane & 15;
    const int g    = lane >> 4;
    const int m0   = (w >> 1) * 64;   // k-split
    const int n0   = (w & 1) * 64;    // q-split

    // ---- stage q, q2 once, then hoist frags to registers ----
    {
        const unsigned short* qb  = qh  + ((size_t)bh * 2048 + qt * 128) * 64;
        const unsigned short* q2b = q2h + ((size_t)bh * 2048 + qt * 128) * 64;
        const int row = t >> 1;
        #pragma unroll
        for (int c = 0; c < 4; ++c) {
            int cg  = (t & 1) * 4 + c;
            short8 a  = *(const short8*)(qb  + (size_t)row * 64 + cg * 8);
            short8 a2 = *(const short8*)(q2b + (size_t)row * 64 + cg * 8);
            int cgm = (cg + row) & 7;
            *(short8*)&qs [row * 64 + cgm * 8] = a;
            *(short8*)&q2s[row * 64 + cgm * 8] = a2;
        }
    }
    __syncthreads();
    short8 bq[2][4], bq2[2][4];
    #pragma unroll
    for (int kstep = 0; kstep < 2; ++kstep) {
        const int gl = kstep * 4 + g;
        #pragma unroll
        for (int j = 0; j < 4; ++j) {
            int row = n0 + j * 16 + s;
            int a = row * 64 + ((gl + row) & 7) * 8;
            bq[kstep][j]  = *(const short8*)&qs [a];
            bq2[kstep][j] = *(const short8*)&q2s[a];
        }
    }

    floatx4 zac[2][4];
    #pragma unroll
    for (int i = 0; i < 2; ++i)
        #pragma unroll
        for (int j = 0; j < 4; ++j)
            zac[i][j] = (floatx4)(0.0f);

    for (int tk = 0; tk <= qt; ++tk) {
        // ---- register prefetch ----
        short8 kf[4], k2f[4], vf[4];
        {
            const unsigned short* kb  = kh  + ((size_t)bh * 2048 + tk * 128) * 64;
            const unsigned short* k2b = k2h + ((size_t)bh * 2048 + tk * 128) * 64;
            const unsigned short* vb  = vt  + (size_t)bh * 131072 + tk * 128;
            const int krow = t >> 1;
            const int vd   = t >> 2;
            #pragma unroll
            for (int c = 0; c < 4; ++c) {
                int cg = (t & 1) * 4 + c;
                kf[c]  = *(const short8*)(kb  + (size_t)krow * 64 + cg * 8);
                k2f[c] = *(const short8*)(k2b + (size_t)krow * 64 + cg * 8);
                int cg16 = 4 * (t & 3) + c;
                vf[c]  = *(const short8*)(vb + (size_t)vd * 2048 + cg16 * 8);
            }
        }
        __syncthreads();   // b0: prev PV done (psq/vts); prev S done (ks/k2s); q-hoist done
        {
            const int krow = t >> 1;
            const int vd   = t >> 2;
            #pragma unroll
            for (int c = 0; c < 4; ++c) {
                int cg  = (t & 1) * 4 + c;
                int cgm = (cg + krow) & 7;
                *(short8*)&ks [krow * 64 + cgm * 8] = kf[c];
                *(short8*)&k2s[krow * 64 + cgm * 8] = k2f[c];
                int cg16  = 4 * (t & 3) + c;
                int cgm16 = (cg16 + vd) & 15;
                *(short8*)&vts[vd * 128 + cgm16 * 8] = vf[c];
            }
        }
        __syncthreads();   // b1: tiles visible

        // ---- S + P, i-outer (a1/a2 footprint = one i at a time) ----
        #pragma unroll
        for (int i = 0; i < 4; ++i) {
            floatx4 a1[4], a2[4];
            #pragma unroll
            for (int j = 0; j < 4; ++j) { a1[j] = (floatx4)(0.0f); a2[j] = (floatx4)(0.0f); }
            #pragma unroll
            for (int kstep = 0; kstep < 2; ++kstep) {
                const int gl = kstep * 4 + g;
                int row = m0 + i * 16 + s;
                int a = row * 64 + ((gl + row) & 7) * 8;
                short8 ak  = *(const short8*)&ks [a];
                short8 ak2 = *(const short8*)&k2s[a];
                #pragma unroll
                for (int j = 0; j < 4; ++j) {
                    a1[j] = __builtin_amdgcn_mfma_f32_16x16x32_bf16(ak,  bq[kstep][j],  a1[j], 0, 0, 0);
                    a2[j] = __builtin_amdgcn_mfma_f32_16x16x32_bf16(ak2, bq2[kstep][j], a2[j], 0, 0, 0);
                }
            }
            // P-write for this i: psq region unread by anyone during the loop
            const int kl0   = m0 + i * 16 + g * 4;
            const int chunk = kl0 >> 3;
            const int sub   = kl0 & 7;
            if (tk < qt) {
                #pragma unroll
                for (int j = 0; j < 4; ++j) {
                    const int ql = n0 + j * 16 + s;
                    ushort4 pw;
                    pw.x = f2bf(a1[j][0] * a2[j][0]);
                    pw.y = f2bf(a1[j][1] * a2[j][1]);
                    pw.z = f2bf(a1[j][2] * a2[j][2]);
                    pw.w = f2bf(a1[j][3] * a2[j][3]);
                    *(ushort4*)&psq[ql * 128 + ((chunk + ql) & 15) * 8 + sub] = pw;
                }
            } else {
                #pragma unroll
                for (int j = 0; j < 4; ++j) {
                    const int ql = n0 + j * 16 + s;
                    ushort4 pw;
                    pw.x = (kl0 + 0 <= ql) ? f2bf(a1[j][0] * a2[j][0]) : (unsigned short)0;
                    pw.y = (kl0 + 1 <= ql) ? f2bf(a1[j][1] * a2[j][1]) : (unsigned short)0;
                    pw.z = (kl0 + 2 <= ql) ? f2bf(a1[j][2] * a2[j][2]) : (unsigned short)0;
                    pw.w = (kl0 + 3 <= ql) ? f2bf(a1[j][3] * a2[j][3]) : (unsigned short)0;
                    *(ushort4*)&psq[ql * 128 + ((chunk + ql) & 15) * 8 + sub] = pw;
                }
            }
        }

        __syncthreads();   // b2: psq visible

        // ---- PV: z[q][d] += P[q][k] * vT[d][k] ----
        const int wm0 = w * 32;
        #pragma unroll
        for (int kstep = 0; kstep < 4; ++kstep) {
            const int cbase = kstep * 4 + g;
            short8 ap[2], bv[4];
            #pragma unroll
            for (int i2 = 0; i2 < 2; ++i2) {
                int q = wm0 + i2 * 16 + s;
                ap[i2] = *(const short8*)&psq[q * 128 + ((cbase + q) & 15) * 8];
            }
            #pragma unroll
            for (int jd = 0; jd < 4; ++jd) {
                int d = jd * 16 + s;
                bv[jd] = *(const short8*)&vts[d * 128 + ((cbase + d) & 15) * 8];
            }
            #pragma unroll
            for (int i2 = 0; i2 < 2; ++i2)
                #pragma unroll
                for (int jd = 0; jd < 4; ++jd)
                    zac[i2][jd] = __builtin_amdgcn_mfma_f32_16x16x32_bf16(ap[i2], bv[jd], zac[i2][jd], 0, 0, 0);
        }
    }

    // ---- epilogue: z -> split bf16 [hi | lo] into zout[4096][2048] ----
    const int b = bh >> 4, h = bh & 15;
    const size_t zrow0 = (size_t)(b * TSEQ + qt * 128);
    #pragma unroll
    for (int i2 = 0; i2 < 2; ++i2)
        #pragma unroll
        for (int j = 0; j < 4; ++j)
            #pragma unroll
            for (int r = 0; r < 4; ++r) {
                float zv = zac[i2][j][r];
                unsigned short hi = f2bf(zv);
                unsigned short lo = f2bf(zv - bf2f(hi));
                size_t row = zrow0 + w * 32 + i2 * 16 + g * 4 + r;
                int col = h * 64 + j * 16 + s;
                zout[row * 2048 + col]        = hi;
                zout[row * 2048 + 1024 + col] = lo;
            }
}

// ---------------------------------------------------------------------------
extern "C" void kernel_launch(void* const* d_in, const int* in_sizes, int n_in,
                              void* d_out, int out_size, void* d_ws, size_t ws_size,
                              hipStream_t stream)
{
    const float* x     = (const float*)d_in[0];
    const float* Wq    = (const float*)d_in[1];
    const float* Wk    = (const float*)d_in[2];
    const float* Wq2   = (const float*)d_in[3];
    const float* Wk2   = (const float*)d_in[4];
    const float* Wv    = (const float*)d_in[5];
    const float* Wproj = (const float*)d_in[6];

    // workspace (bytes):
    //   Xp    bf16 [4096][2048] (x-split, later z-split) @ 0          (16,777,216)
    //   Wp    bf16 [6144][2048]                          @ 16,777,216 (25,165,824)
    //         rows [0,1024)    = Wproj [hi|lo]
    //         rows [1024,6144) = Wq,Wk,Wq2,Wk2 (head-interleaved), Wv [hi|hi]
    //   heads bf16 4x[32][2048][64] (q,k,q2,k2)          @ 41,943,040 (33,554,432)
    //   vt    bf16 [32][64][2048]                        @ 75,497,472 ( 8,388,608)
    unsigned short* Xp    = (unsigned short*)d_ws;
    unsigned short* Wp    = (unsigned short*)((char*)d_ws + 16777216);
    unsigned short* heads = (unsigned short*)((char*)d_ws + 41943040);
    unsigned short* vt    = (unsigned short*)((char*)d_ws + 75497472);

    const size_t HS = (size_t)32 * 2048 * 64;
    unsigned short* qh  = heads;
    unsigned short* kh  = heads + 1 * HS;
    unsigned short* q2h = heads + 2 * HS;
    unsigned short* k2h = heads + 3 * HS;

    pack_all_kernel<<<10240, 256, 0, stream>>>(x, Wproj, Wq, Wk, Wq2, Wk2, Wv, Xp, Wp);
    gemm_qkv<<<dim3(16, 16), 512, 0, stream>>>(Xp, Wp + (size_t)1024 * 2048, heads, vt);
    attn_mfma<<<dim3(16, 32), 256, 0, stream>>>(qh, q2h, kh, k2h, vt, Xp);
    gemm_proj<<<dim3(32, 16), 256, 0, stream>>>(Xp, Wp, (float*)d_out);
}